// Round 10
// baseline (1345.298 us; speedup 1.0000x reference)
//
#include <hip/hip_runtime.h>
#include <hip/hip_bf16.h>
#include <cstdint>
#include <cstddef>

typedef __attribute__((ext_vector_type(8))) short short8;   // 8 bf16 = 4 VGPRs (MFMA A/B frag)
typedef __attribute__((ext_vector_type(4))) float f32x4;    // MFMA C/D frag (also nt-load vec)

__device__ __forceinline__ unsigned short f2bf(float f) {
  unsigned u = __float_as_uint(f);
  unsigned r = (u + 0x7fffu + ((u >> 16) & 1u)) >> 16;   // RNE
  return (unsigned short)r;
}
__device__ __forceinline__ float bf2f(unsigned short b) {
  return __uint_as_float(((unsigned)b) << 16);
}
// order-preserving float -> uint key for atomicMax (0 sentinel < every real key)
__device__ __forceinline__ unsigned fkey(float f) {
  unsigned b = __float_as_uint(f);
  return (b & 0x80000000u) ? ~b : (b | 0x80000000u);
}

// ---------------------------------------------------------------------------
// Pack W1a [256(k) x 256(col)] fp32 -> bf16 in MFMA-B-fragment order:
// packedB[((s*32 + kk*4+quad)*64 + n)*8 + j] = bf16(W1a[kk*32+quad*8+j][s*64+n])
// (s = col>>6 stage, n = col&63). A lane's b-frag is one contiguous 16B read.
// ---------------------------------------------------------------------------
__global__ __launch_bounds__(256)
void prep_b_kernel(const float* __restrict__ W1a, unsigned short* __restrict__ packedB) {
  int idx = blockIdx.x * 256 + threadIdx.x;   // 0..65535
  int j  = idx & 7;
  int n  = (idx >> 3) & 63;
  int kq = (idx >> 9) & 31;                   // kk*4 + quad
  int s  = idx >> 14;                         // column stage (64 cols each)
  int k  = (kq >> 2) * 32 + (kq & 3) * 8 + j;
  int col = s * 64 + n;
  packedB[idx] = f2bf(W1a[k * 256 + col]);
}

// score epilogue: fold acc -> partial attention score, reduce over 16 lanes (m)
__device__ __forceinline__ void score_store(const f32x4 acc[4], const float b1r[4],
                                            const float w2r[4], float* dst,
                                            int m, int quad) {
  float p[4];
  #pragma unroll
  for (int r = 0; r < 4; ++r) {
    float s = 0.f;
    #pragma unroll
    for (int nb = 0; nb < 4; ++nb)
      s += fmaxf(acc[nb][r] + b1r[nb], 0.f) * w2r[nb];
    p[r] = s;
  }
  #pragma unroll
  for (int off = 1; off < 16; off <<= 1) {
    #pragma unroll
    for (int r = 0; r < 4; ++r) p[r] += __shfl_xor(p[r], off, 64);
  }
  if (m == 0) {
    #pragma unroll
    for (int r = 0; r < 4; ++r) dst[quad * 4 + r] = p[r];
  }
}

// ---------------------------------------------------------------------------
// Fused phase-A, 4-wave 256-thread WGs on 32-node tiles. Wave = cg (64 hidden
// cols / 64 pooling channels); each wave scans ALL 32 nodes of the tile.
// WHY 256-thr: round-9 measured residency stuck at 2 WGs/CU for 512-thr WGs
// (occ 42.6% with grid 512 AND 1024; LDS/VGPR allow 4) -> WG shape is the
// binding constraint. 17.9KB LDS -> 8 WGs/CU (32 waves) now fit.
// B streamed from L2; ballot run-detection; direct atomic flush per run
// (sum/max associative); contiguous tile chunks per block; nt x loads.
// ---------------------------------------------------------------------------
__global__ __launch_bounds__(256, 8)
void phase_a_kernel(const float* __restrict__ x, const int* __restrict__ batch,
                    const unsigned short* __restrict__ packedB,
                    const float* __restrict__ b1a, const float* __restrict__ W2a,
                    const float* __restrict__ b2a,
                    float* __restrict__ attbuf, float* __restrict__ sumbuf,
                    unsigned* __restrict__ maxkey, float* __restrict__ cntbuf,
                    int nnodes, int ntiles, int tpb) {
  __shared__ __align__(16) unsigned short sX[32][264];   // bf16 x tile, +8 pad/row
  __shared__ float sScoreP[4][32];                       // per-chan-group score partials
  __shared__ float sAw[32];
  __shared__ int   sBatch[32];
  __shared__ int   sRunStart[33];                        // run starts + sentinel
  __shared__ int   sSeg[32];                             // seg id per run
  __shared__ int   sNruns;

  const int t = threadIdx.x;
  const int lane = t & 63;
  const int cg = t >> 6;          // wave id = channel group: cols [cg*64, cg*64+64)
  const int m = lane & 15;
  const int quad = lane >> 4;
  const int chan = cg * 64 + lane;   // channel owned in the pooling scan

  float b1r[4], w2r[4];
  #pragma unroll
  for (int nb = 0; nb < 4; ++nb) {
    int col = cg * 64 + nb * 16 + m;
    b1r[nb] = b1a[col];
    w2r[nb] = W2a[col];
  }
  const float b2 = b2a[0];

  // per-lane base into packedB; frag (kk,nb) at +kk*2048 + nb*128 elements
  const unsigned short* Bbase = packedB + (size_t)((cg * 32 + quad) * 64 + m) * 8;

  const int tile0 = blockIdx.x * tpb;
  const int tile1 = min(ntiles, tile0 + tpb);
  for (int tile = tile0; tile < tile1; ++tile) {
    const int block0 = tile * 32;
    const int nvalid = min(32, nnodes - block0);

    if (t < 32) sBatch[t] = (t < nvalid) ? batch[block0 + t] : -1;

    // stage x tile (32 x 256 fp32) -> bf16 LDS, coalesced nontemporal float4
    // (each wave covers one full 1KB row per sub-iter -> 8-line fills, no waste)
    #pragma unroll
    for (int it = 0; it < 8; ++it) {
      int idx = it * 256 + t;       // float4 slot 0..2047
      int row = idx >> 6;           // 0..31
      int c4  = idx & 63;
      f32x4 v = {0.f, 0.f, 0.f, 0.f};
      if (block0 + row < nnodes)
        v = __builtin_nontemporal_load(
              reinterpret_cast<const f32x4*>(x) + (size_t)(block0 + row) * 64 + c4);
      ushort4 h;
      h.x = f2bf(v.x); h.y = f2bf(v.y); h.z = f2bf(v.z); h.w = f2bf(v.w);
      *reinterpret_cast<ushort4*>(&sX[row][c4 * 4]) = h;
    }
    __syncthreads();   // (1) tile staged

    // GEMM: wave cg computes h[:, cg*64 : cg*64+64] for all 32 nodes
    {
      f32x4 acc0[4] = {{0,0,0,0},{0,0,0,0},{0,0,0,0},{0,0,0,0}};
      f32x4 acc1[4] = {{0,0,0,0},{0,0,0,0},{0,0,0,0},{0,0,0,0}};
      #pragma unroll
      for (int kk = 0; kk < 8; ++kk) {
        short8 Bt[4];
        #pragma unroll
        for (int nb = 0; nb < 4; ++nb)
          Bt[nb] = *reinterpret_cast<const short8*>(Bbase + kk * 2048 + nb * 128);
        short8 a0 = *reinterpret_cast<const short8*>(&sX[m][kk * 32 + quad * 8]);
        short8 a1 = *reinterpret_cast<const short8*>(&sX[16 + m][kk * 32 + quad * 8]);
        #pragma unroll
        for (int nb = 0; nb < 4; ++nb) {
          acc0[nb] = __builtin_amdgcn_mfma_f32_16x16x32_bf16(a0, Bt[nb], acc0[nb], 0, 0, 0);
          acc1[nb] = __builtin_amdgcn_mfma_f32_16x16x32_bf16(a1, Bt[nb], acc1[nb], 0, 0, 0);
        }
      }
      score_store(acc0, b1r, w2r, &sScoreP[cg][0],  m, quad);   // nodes 0..15
      score_store(acc1, b1r, w2r, &sScoreP[cg][16], m, quad);   // nodes 16..31
    }
    __syncthreads();   // (2) score partials ready

    if (t < 32) {   // first half of wave 0
      float s = sScoreP[0][t] + sScoreP[1][t] + sScoreP[2][t] + sScoreP[3][t] + b2;
      sAw[t] = 1.f / (1.f + __expf(-s));

      // run structure via ballot over sorted batch ids (bits 32..63 inactive -> 0)
      int b = sBatch[t];
      bool valid = t < nvalid;
      bool isStart = valid && (t == 0 || sBatch[t - 1] != b);
      unsigned long long mask = __ballot(isStart);
      if (isStart) {
        int rid = __popcll(mask & ((1ull << t) - 1ull));
        sRunStart[rid] = t;
        sSeg[rid] = b;
        unsigned long long rest = mask >> (t + 1);   // t<=31 -> shift <=32, defined
        int nxt = rest ? (t + __ffsll((long long)rest)) : nvalid;   // next start or end
        atomicAdd(&cntbuf[b], (float)(nxt - t));                    // exact run length
      }
      if (t == 0) { int nr = __popcll(mask); sNruns = nr; sRunStart[nr] = nvalid; }
    }
    __syncthreads();   // (3) aw + run table ready

    // pooling scan: wave cg covers its 64 chans x all nvalid nodes; every run
    // flushed directly via atomics (associative ops)
    {
      const int nr = sNruns;
      for (int r = 0; r < nr; ++r) {
        int rs = sRunStart[r];
        int re = sRunStart[r + 1];                 // <= nvalid by construction
        float aS = 0.f, aA = 0.f, aM = -INFINITY;
        for (int i = rs; i < re; ++i) {
          float xv = bf2f(sX[i][chan]);
          float awv = sAw[i];                      // broadcast read
          aS += xv;
          aA = fmaf(xv, awv, aA);
          aM = fmaxf(aM, xv);
        }
        int seg = sSeg[r];
        atomicAdd(&sumbuf[(size_t)seg * 256 + chan], aS);
        atomicAdd(&attbuf[(size_t)seg * 256 + chan], aA);
        atomicMax(&maxkey[(size_t)seg * 256 + chan], fkey(aM));
      }
    }
    __syncthreads();   // (4) protect sX + run table before next tile's staging
  }
}

// ---------------------------------------------------------------------------
// Final MLP: out[g] = relu(comb[g] @ W1f + b1f) @ W2f + b2f, 4 graphs/block
// (1024 blocks -> good latency hiding), rank-1-update formulation.
// ---------------------------------------------------------------------------
__global__ __launch_bounds__(256, 4)
void final_mlp_kernel(const float* __restrict__ attbuf, const float* __restrict__ sumbuf,
                      const unsigned* __restrict__ maxkey, const float* __restrict__ cntbuf,
                      const float* __restrict__ W1f, const float* __restrict__ b1f,
                      const float* __restrict__ W2f, const float* __restrict__ b2f,
                      float* __restrict__ out) {
  __shared__ float sComb[4 * 768];
  __shared__ float sHid[4 * 256];
  const int t = threadIdx.x;
  const int g0 = blockIdx.x * 4;

  for (int idx = t; idx < 4 * 768; idx += 256) {
    int g = idx / 768;
    int k = idx - g * 768;
    int gg = g0 + g;
    float cnt = cntbuf[gg];
    float v;
    if (k < 256) {
      v = attbuf[(size_t)gg * 256 + k];
    } else if (k < 512) {
      v = sumbuf[(size_t)gg * 256 + (k - 256)] / fmaxf(cnt, 1.f);
    } else {
      unsigned u = maxkey[(size_t)gg * 256 + (k - 512)];
      unsigned b = (u & 0x80000000u) ? (u & 0x7fffffffu) : ~u;
      v = (cnt > 0.f) ? __uint_as_float(b) : 0.f;   // empty segment -> 0
    }
    sComb[idx] = v;
  }
  __syncthreads();

  float acc[4] = {0, 0, 0, 0};
  #pragma unroll 4
  for (int k = 0; k < 768; ++k) {
    float wv = W1f[k * 256 + t];
    #pragma unroll
    for (int g = 0; g < 4; ++g) acc[g] = fmaf(sComb[g * 768 + k], wv, acc[g]);
  }
  float bb = b1f[t];
  #pragma unroll
  for (int g = 0; g < 4; ++g) sHid[g * 256 + t] = fmaxf(acc[g] + bb, 0.f);
  __syncthreads();

  float acc2[4] = {0, 0, 0, 0};
  #pragma unroll 4
  for (int k = 0; k < 256; ++k) {
    float wv = W2f[k * 256 + t];
    #pragma unroll
    for (int g = 0; g < 4; ++g) acc2[g] = fmaf(sHid[g * 256 + k], wv, acc2[g]);
  }
  float bo = b2f[t];
  #pragma unroll
  for (int g = 0; g < 4; ++g) out[(size_t)(g0 + g) * 256 + t] = acc2[g] + bo;
}

// ---------------------------------------------------------------------------
extern "C" void kernel_launch(void* const* d_in, const int* in_sizes, int n_in,
                              void* d_out, int out_size, void* d_ws, size_t ws_size,
                              hipStream_t stream) {
  const float* x   = (const float*)d_in[0];
  const int* batch = (const int*)d_in[1];
  const float* W1a = (const float*)d_in[2];
  const float* b1a = (const float*)d_in[3];
  const float* W2a = (const float*)d_in[4];
  const float* b2a = (const float*)d_in[5];
  const float* W1f = (const float*)d_in[6];
  const float* b1f = (const float*)d_in[7];
  const float* W2f = (const float*)d_in[8];
  const float* b2f = (const float*)d_in[9];
  float* out = (float*)d_out;

  const int N = in_sizes[0] / 256;
  const int G = out_size / 256;

  char* ws = (char*)d_ws;
  float* attbuf = (float*)ws;
  float* sumbuf = attbuf + (size_t)G * 256;
  unsigned* maxkey = (unsigned*)(sumbuf + (size_t)G * 256);
  float* cntbuf = (float*)(maxkey + (size_t)G * 256);
  unsigned short* packedB = (unsigned short*)(cntbuf + G);

  size_t zero_bytes = ((size_t)G * 256 * 3 + G) * sizeof(float);
  (void)hipMemsetAsync(d_ws, 0, zero_bytes, stream);

  prep_b_kernel<<<256, 256, 0, stream>>>(W1a, packedB);

  int ntiles = (N + 31) / 32;        // 32-node tiles now
  const int nblocks = 2048;          // 8 WGs/CU target (17.9KB LDS x 8 fits 160KB)
  int tpb = (ntiles + nblocks - 1) / nblocks;
  phase_a_kernel<<<nblocks, 256, 0, stream>>>(x, batch, packedB, b1a, W2a, b2a,
                                              attbuf, sumbuf, maxkey, cntbuf,
                                              N, ntiles, tpb);

  final_mlp_kernel<<<G / 4, 256, 0, stream>>>(attbuf, sumbuf, maxkey, cntbuf,
                                              W1f, b1f, W2f, b2f, out);
}

// Round 11
// 926.493 us; speedup vs baseline: 1.4520x; 1.4520x over previous
//
#include <hip/hip_runtime.h>
#include <hip/hip_bf16.h>
#include <cstdint>
#include <cstddef>

typedef __attribute__((ext_vector_type(8))) short short8;   // 8 bf16 = 4 VGPRs (MFMA A/B frag)
typedef __attribute__((ext_vector_type(4))) float f32x4;    // MFMA C/D frag (also load vec)

__device__ __forceinline__ unsigned short f2bf(float f) {
  unsigned u = __float_as_uint(f);
  unsigned r = (u + 0x7fffu + ((u >> 16) & 1u)) >> 16;   // RNE
  return (unsigned short)r;
}
__device__ __forceinline__ float bf2f(unsigned short b) {
  return __uint_as_float(((unsigned)b) << 16);
}
// order-preserving float -> uint key for atomicMax (0 sentinel < every real key)
__device__ __forceinline__ unsigned fkey(float f) {
  unsigned b = __float_as_uint(f);
  return (b & 0x80000000u) ? ~b : (b | 0x80000000u);
}

// ---------------------------------------------------------------------------
// Pack W1a [256(k) x 256(col)] fp32 -> bf16 in MFMA-B-fragment order:
// packedB[((s*32 + kk*4+quad)*64 + n)*8 + j] = bf16(W1a[kk*32+quad*8+j][s*64+n])
// (s = col>>6 stage, n = col&63). A lane's b-frag is one contiguous 16B read.
// ---------------------------------------------------------------------------
__global__ __launch_bounds__(256)
void prep_b_kernel(const float* __restrict__ W1a, unsigned short* __restrict__ packedB) {
  int idx = blockIdx.x * 256 + threadIdx.x;   // 0..65535
  int j  = idx & 7;
  int n  = (idx >> 3) & 63;
  int kq = (idx >> 9) & 31;                   // kk*4 + quad
  int s  = idx >> 14;                         // column stage (64 cols each)
  int k  = (kq >> 2) * 32 + (kq & 3) * 8 + j;
  int col = s * 64 + n;
  packedB[idx] = f2bf(W1a[k * 256 + col]);
}

// score epilogue: fold acc -> partial attention score, reduce over 16 lanes (m)
__device__ __forceinline__ void score_store(const f32x4 acc[4], const float b1r[4],
                                            const float w2r[4], float* dst,
                                            int m, int quad) {
  float p[4];
  #pragma unroll
  for (int r = 0; r < 4; ++r) {
    float s = 0.f;
    #pragma unroll
    for (int nb = 0; nb < 4; ++nb)
      s += fmaxf(acc[nb][r] + b1r[nb], 0.f) * w2r[nb];
    p[r] = s;
  }
  #pragma unroll
  for (int off = 1; off < 16; off <<= 1) {
    #pragma unroll
    for (int r = 0; r < 4; ++r) p[r] += __shfl_xor(p[r], off, 64);
  }
  if (m == 0) {
    #pragma unroll
    for (int r = 0; r < 4; ++r) dst[quad * 4 + r] = p[r];
  }
}

// ---------------------------------------------------------------------------
// Fused phase-A, 4-wave 256-thr WGs on 64-node tiles. Wave = cg (64 hidden
// cols / 64 pooling channels); each wave computes all 4 node-subtiles (mt)
// and scans ALL 64 nodes for its channels.
// EVIDENCE-DRIVEN CHOICES (R6/R9/R10 counters):
//  - BW pinned at 2.76 TB/s across 42%..80% occupancy -> byte count is the
//    cost function, occupancy is NOT. So:
//  - Bfrag REGISTER-RESIDENT (128 VGPR/wave): kills the ~2GB/launch packedB
//    L2 stream whose HBM-miss portion was 0.45-1.0 GB of FETCH overage.
//  - x loads are PLAIN (no nontemporal): 2.76 ceiling appeared with nt in
//    every config; the 6.3 TB/s ubench uses normal loads. hbm_gbps tells.
//  - 64-node tiles halve atomic run-pieces + per-tile fixed costs vs 32.
// Ballot run-detection; direct atomic flush per run (sum/max associative).
// ---------------------------------------------------------------------------
__global__ __launch_bounds__(256, 2)
void phase_a_kernel(const float* __restrict__ x, const int* __restrict__ batch,
                    const unsigned short* __restrict__ packedB,
                    const float* __restrict__ b1a, const float* __restrict__ W2a,
                    const float* __restrict__ b2a,
                    float* __restrict__ attbuf, float* __restrict__ sumbuf,
                    unsigned* __restrict__ maxkey, float* __restrict__ cntbuf,
                    int nnodes, int ntiles, int tpb) {
  __shared__ __align__(16) unsigned short sX[64][264];   // bf16 x tile, +8 pad/row
  __shared__ float sScoreP[4][64];                       // per-chan-group score partials
  __shared__ float sAw[64];
  __shared__ int   sBatch[64];
  __shared__ int   sRunStart[65];                        // run starts + sentinel
  __shared__ int   sSeg[64];                             // seg id per run
  __shared__ int   sNruns;

  const int t = threadIdx.x;
  const int lane = t & 63;
  const int cg = t >> 6;          // wave id = channel group: cols [cg*64, cg*64+64)
  const int m = lane & 15;
  const int quad = lane >> 4;
  const int chan = cg * 64 + lane;   // channel owned in the pooling scan

  // --- resident B fragments (once per block; 128 KB read once per block) ---
  short8 Bfrag[8][4];
  #pragma unroll
  for (int kk = 0; kk < 8; ++kk) {
    #pragma unroll
    for (int nb = 0; nb < 4; ++nb) {
      Bfrag[kk][nb] = *reinterpret_cast<const short8*>(
          packedB + (size_t)((cg * 32 + kk * 4 + quad) * 64 + nb * 16 + m) * 8);
    }
  }
  float b1r[4], w2r[4];
  #pragma unroll
  for (int nb = 0; nb < 4; ++nb) {
    int col = cg * 64 + nb * 16 + m;
    b1r[nb] = b1a[col];
    w2r[nb] = W2a[col];
  }
  const float b2 = b2a[0];

  const int tile0 = blockIdx.x * tpb;
  const int tile1 = min(ntiles, tile0 + tpb);
  for (int tile = tile0; tile < tile1; ++tile) {
    const int block0 = tile * 64;
    const int nvalid = min(64, nnodes - block0);

    if (t < 64) sBatch[t] = (t < nvalid) ? batch[block0 + t] : -1;

    // stage x tile (64 x 256 fp32) -> bf16 LDS, coalesced plain float4 loads
    #pragma unroll
    for (int it = 0; it < 16; ++it) {
      int idx = it * 256 + t;       // float4 slot 0..4095
      int row = idx >> 6;           // 0..63
      int c4  = idx & 63;
      f32x4 v = {0.f, 0.f, 0.f, 0.f};
      if (block0 + row < nnodes)
        v = *(reinterpret_cast<const f32x4*>(x) + (size_t)(block0 + row) * 64 + c4);
      ushort4 h;
      h.x = f2bf(v.x); h.y = f2bf(v.y); h.z = f2bf(v.z); h.w = f2bf(v.w);
      *reinterpret_cast<ushort4*>(&sX[row][c4 * 4]) = h;
    }
    __syncthreads();   // (1) tile staged

    // GEMM: wave cg computes h[:, cg*64 .. cg*64+64) for all 64 nodes (4 mt)
    #pragma unroll
    for (int mt = 0; mt < 4; ++mt) {
      f32x4 acc[4] = {{0,0,0,0},{0,0,0,0},{0,0,0,0},{0,0,0,0}};
      #pragma unroll
      for (int kk = 0; kk < 8; ++kk) {
        short8 af = *reinterpret_cast<const short8*>(&sX[mt * 16 + m][kk * 32 + quad * 8]);
        #pragma unroll
        for (int nb = 0; nb < 4; ++nb)
          acc[nb] = __builtin_amdgcn_mfma_f32_16x16x32_bf16(af, Bfrag[kk][nb], acc[nb], 0, 0, 0);
      }
      score_store(acc, b1r, w2r, &sScoreP[cg][mt * 16], m, quad);
    }
    __syncthreads();   // (2) score partials ready

    if (t < 64) {   // wave 0 exactly
      float s = sScoreP[0][t] + sScoreP[1][t] + sScoreP[2][t] + sScoreP[3][t] + b2;
      sAw[t] = 1.f / (1.f + __expf(-s));

      // run structure via ballot over sorted batch ids
      int b = sBatch[t];
      bool valid = t < nvalid;
      bool isStart = valid && (t == 0 || sBatch[t - 1] != b);
      unsigned long long mask = __ballot(isStart);
      if (isStart) {
        int rid = __popcll(mask & ((1ull << t) - 1ull));
        sRunStart[rid] = t;
        sSeg[rid] = b;
        unsigned long long rest = (t < 63) ? (mask >> (t + 1)) : 0ull;
        int nxt = rest ? (t + __ffsll((long long)rest)) : nvalid;   // next start or end
        atomicAdd(&cntbuf[b], (float)(nxt - t));                    // exact run length
      }
      if (t == 0) { int nr = __popcll(mask); sNruns = nr; sRunStart[nr] = nvalid; }
    }
    __syncthreads();   // (3) aw + run table ready

    // pooling scan: wave cg covers its 64 chans x all nvalid nodes; every run
    // flushed directly via atomics (associative ops)
    {
      const int nr = sNruns;
      for (int r = 0; r < nr; ++r) {
        int rs = sRunStart[r];
        int re = sRunStart[r + 1];                 // <= nvalid by construction
        float aS = 0.f, aA = 0.f, aM = -INFINITY;
        for (int i = rs; i < re; ++i) {
          float xv = bf2f(sX[i][chan]);
          float awv = sAw[i];                      // broadcast read
          aS += xv;
          aA = fmaf(xv, awv, aA);
          aM = fmaxf(aM, xv);
        }
        int seg = sSeg[r];
        atomicAdd(&sumbuf[(size_t)seg * 256 + chan], aS);
        atomicAdd(&attbuf[(size_t)seg * 256 + chan], aA);
        atomicMax(&maxkey[(size_t)seg * 256 + chan], fkey(aM));
      }
    }
    __syncthreads();   // (4) protect sX + run table before next tile's staging
  }
}

// ---------------------------------------------------------------------------
// Final MLP: out[g] = relu(comb[g] @ W1f + b1f) @ W2f + b2f, 4 graphs/block
// (1024 blocks -> good latency hiding), rank-1-update formulation.
// ---------------------------------------------------------------------------
__global__ __launch_bounds__(256, 4)
void final_mlp_kernel(const float* __restrict__ attbuf, const float* __restrict__ sumbuf,
                      const unsigned* __restrict__ maxkey, const float* __restrict__ cntbuf,
                      const float* __restrict__ W1f, const float* __restrict__ b1f,
                      const float* __restrict__ W2f, const float* __restrict__ b2f,
                      float* __restrict__ out) {
  __shared__ float sComb[4 * 768];
  __shared__ float sHid[4 * 256];
  const int t = threadIdx.x;
  const int g0 = blockIdx.x * 4;

  for (int idx = t; idx < 4 * 768; idx += 256) {
    int g = idx / 768;
    int k = idx - g * 768;
    int gg = g0 + g;
    float cnt = cntbuf[gg];
    float v;
    if (k < 256) {
      v = attbuf[(size_t)gg * 256 + k];
    } else if (k < 512) {
      v = sumbuf[(size_t)gg * 256 + (k - 256)] / fmaxf(cnt, 1.f);
    } else {
      unsigned u = maxkey[(size_t)gg * 256 + (k - 512)];
      unsigned b = (u & 0x80000000u) ? (u & 0x7fffffffu) : ~u;
      v = (cnt > 0.f) ? __uint_as_float(b) : 0.f;   // empty segment -> 0
    }
    sComb[idx] = v;
  }
  __syncthreads();

  float acc[4] = {0, 0, 0, 0};
  #pragma unroll 4
  for (int k = 0; k < 768; ++k) {
    float wv = W1f[k * 256 + t];
    #pragma unroll
    for (int g = 0; g < 4; ++g) acc[g] = fmaf(sComb[g * 768 + k], wv, acc[g]);
  }
  float bb = b1f[t];
  #pragma unroll
  for (int g = 0; g < 4; ++g) sHid[g * 256 + t] = fmaxf(acc[g] + bb, 0.f);
  __syncthreads();

  float acc2[4] = {0, 0, 0, 0};
  #pragma unroll 4
  for (int k = 0; k < 256; ++k) {
    float wv = W2f[k * 256 + t];
    #pragma unroll
    for (int g = 0; g < 4; ++g) acc2[g] = fmaf(sHid[g * 256 + k], wv, acc2[g]);
  }
  float bo = b2f[t];
  #pragma unroll
  for (int g = 0; g < 4; ++g) out[(size_t)(g0 + g) * 256 + t] = acc2[g] + bo;
}

// ---------------------------------------------------------------------------
extern "C" void kernel_launch(void* const* d_in, const int* in_sizes, int n_in,
                              void* d_out, int out_size, void* d_ws, size_t ws_size,
                              hipStream_t stream) {
  const float* x   = (const float*)d_in[0];
  const int* batch = (const int*)d_in[1];
  const float* W1a = (const float*)d_in[2];
  const float* b1a = (const float*)d_in[3];
  const float* W2a = (const float*)d_in[4];
  const float* b2a = (const float*)d_in[5];
  const float* W1f = (const float*)d_in[6];
  const float* b1f = (const float*)d_in[7];
  const float* W2f = (const float*)d_in[8];
  const float* b2f = (const float*)d_in[9];
  float* out = (float*)d_out;

  const int N = in_sizes[0] / 256;
  const int G = out_size / 256;

  char* ws = (char*)d_ws;
  float* attbuf = (float*)ws;
  float* sumbuf = attbuf + (size_t)G * 256;
  unsigned* maxkey = (unsigned*)(sumbuf + (size_t)G * 256);
  float* cntbuf = (float*)(maxkey + (size_t)G * 256);
  unsigned short* packedB = (unsigned short*)(cntbuf + G);

  size_t zero_bytes = ((size_t)G * 256 * 3 + G) * sizeof(float);
  (void)hipMemsetAsync(d_ws, 0, zero_bytes, stream);

  prep_b_kernel<<<256, 256, 0, stream>>>(W1a, packedB);

  int ntiles = (N + 63) / 64;        // 64-node tiles
  const int nblocks = 1024;
  int tpb = (ntiles + nblocks - 1) / nblocks;
  phase_a_kernel<<<nblocks, 256, 0, stream>>>(x, batch, packedB, b1a, W2a, b2a,
                                              attbuf, sumbuf, maxkey, cntbuf,
                                              N, ntiles, tpb);

  final_mlp_kernel<<<G / 4, 256, 0, stream>>>(attbuf, sumbuf, maxkey, cntbuf,
                                              W1f, b1f, W2f, b2f, out);
}

// Round 12
// 872.593 us; speedup vs baseline: 1.5417x; 1.0618x over previous
//
#include <hip/hip_runtime.h>
#include <hip/hip_bf16.h>
#include <cstdint>
#include <cstddef>

typedef __attribute__((ext_vector_type(8))) short short8;   // 8 bf16 = 4 VGPRs (MFMA A/B frag)
typedef __attribute__((ext_vector_type(4))) float f32x4;    // MFMA C/D frag (also load vec)

__device__ __forceinline__ unsigned short f2bf(float f) {
  unsigned u = __float_as_uint(f);
  unsigned r = (u + 0x7fffu + ((u >> 16) & 1u)) >> 16;   // RNE
  return (unsigned short)r;
}
__device__ __forceinline__ float bf2f(unsigned short b) {
  return __uint_as_float(((unsigned)b) << 16);
}
// order-preserving float -> uint key for atomicMax (0 sentinel < every real key)
__device__ __forceinline__ unsigned fkey(float f) {
  unsigned b = __float_as_uint(f);
  return (b & 0x80000000u) ? ~b : (b | 0x80000000u);
}

// ---------------------------------------------------------------------------
// Pack W1a [256(k) x 256(col)] fp32 -> bf16 in MFMA-B-fragment order:
// packedB[((s*32 + kk*4+quad)*64 + n)*8 + j] = bf16(W1a[kk*32+quad*8+j][s*64+n])
// ---------------------------------------------------------------------------
__global__ __launch_bounds__(256)
void prep_b_kernel(const float* __restrict__ W1a, unsigned short* __restrict__ packedB) {
  int idx = blockIdx.x * 256 + threadIdx.x;   // 0..65535
  int j  = idx & 7;
  int n  = (idx >> 3) & 63;
  int kq = (idx >> 9) & 31;                   // kk*4 + quad
  int s  = idx >> 14;                         // column stage (64 cols each)
  int k  = (kq >> 2) * 32 + (kq & 3) * 8 + j;
  int col = s * 64 + n;
  packedB[idx] = f2bf(W1a[k * 256 + col]);
}

// score epilogue: fold acc -> partial attention score, reduce over 16 lanes (m)
__device__ __forceinline__ void score_store(const f32x4 acc[4], const float b1r[4],
                                            const float w2r[4], float* dst,
                                            int m, int quad) {
  float p[4];
  #pragma unroll
  for (int r = 0; r < 4; ++r) {
    float s = 0.f;
    #pragma unroll
    for (int nb = 0; nb < 4; ++nb)
      s += fmaxf(acc[nb][r] + b1r[nb], 0.f) * w2r[nb];
    p[r] = s;
  }
  #pragma unroll
  for (int off = 1; off < 16; off <<= 1) {
    #pragma unroll
    for (int r = 0; r < 4; ++r) p[r] += __shfl_xor(p[r], off, 64);
  }
  if (m == 0) {
    #pragma unroll
    for (int r = 0; r < 4; ++r) dst[quad * 4 + r] = p[r];
  }
}

// ---------------------------------------------------------------------------
// Fused phase-A, 4-wave 256-thr WGs, 64-node tiles, SOFTWARE-PIPELINED staging.
// EVIDENCE (R6..R11): BW pinned at ~2.76 TB/s regardless of occupancy; time ==
// bytes/2.76TB/s in every config -> duty-cycle theory: staging (loads) and
// compute (GEMM/scan, zero mem traffic with register-resident B) alternate, so
// CUs issue loads only ~60% of the time. Pipeline: after a tile is staged,
// issue HALF the next tile's loads into regs (pf[8], 32 VGPR, in flight across
// GEMM+scan), write them to LDS after barrier(4); load the other half there.
// Bfrag register-resident (kills packedB L2/HBM re-stream, R11 win).
// Ballot run-detection; direct atomic flush per run (associative ops).
// ---------------------------------------------------------------------------
__global__ __launch_bounds__(256, 2)
void phase_a_kernel(const float* __restrict__ x, const int* __restrict__ batch,
                    const unsigned short* __restrict__ packedB,
                    const float* __restrict__ b1a, const float* __restrict__ W2a,
                    const float* __restrict__ b2a,
                    float* __restrict__ attbuf, float* __restrict__ sumbuf,
                    unsigned* __restrict__ maxkey, float* __restrict__ cntbuf,
                    int nnodes, int ntiles, int tpb) {
  __shared__ __align__(16) unsigned short sX[64][264];   // bf16 x tile, +8 pad/row
  __shared__ float sScoreP[4][64];                       // per-chan-group score partials
  __shared__ float sAw[64];
  __shared__ int   sBatch[64];
  __shared__ int   sRunStart[65];                        // run starts + sentinel
  __shared__ int   sSeg[64];                             // seg id per run
  __shared__ int   sNruns;

  const int t = threadIdx.x;
  const int lane = t & 63;
  const int cg = t >> 6;          // wave id = channel group: cols [cg*64, cg*64+64)
  const int m = lane & 15;
  const int quad = lane >> 4;
  const int chan = cg * 64 + lane;   // channel owned in the pooling scan

  // --- resident B fragments (once per block; 128 KB read once per block) ---
  short8 Bfrag[8][4];
  #pragma unroll
  for (int kk = 0; kk < 8; ++kk) {
    #pragma unroll
    for (int nb = 0; nb < 4; ++nb) {
      Bfrag[kk][nb] = *reinterpret_cast<const short8*>(
          packedB + (size_t)((cg * 32 + kk * 4 + quad) * 64 + nb * 16 + m) * 8);
    }
  }
  float b1r[4], w2r[4];
  #pragma unroll
  for (int nb = 0; nb < 4; ++nb) {
    int col = cg * 64 + nb * 16 + m;
    b1r[nb] = b1a[col];
    w2r[nb] = W2a[col];
  }
  const float b2 = b2a[0];

  const int tile0 = blockIdx.x * tpb;
  const int tile1 = min(ntiles, tile0 + tpb);
  if (tile0 >= tile1) return;   // empty chunk (uniform)

  // --- prologue: stage tile0 fully ---
  {
    const int block0 = tile0 * 64;
    const int nvalid = min(64, nnodes - block0);
    if (t < 64) sBatch[t] = (t < nvalid) ? batch[block0 + t] : -1;
    #pragma unroll
    for (int it = 0; it < 16; ++it) {
      int idx = it * 256 + t;
      int row = idx >> 6;
      int c4  = idx & 63;
      f32x4 v = {0.f, 0.f, 0.f, 0.f};
      if (block0 + row < nnodes)
        v = *(reinterpret_cast<const f32x4*>(x) + (size_t)(block0 + row) * 64 + c4);
      ushort4 h;
      h.x = f2bf(v.x); h.y = f2bf(v.y); h.z = f2bf(v.z); h.w = f2bf(v.w);
      *reinterpret_cast<ushort4*>(&sX[row][c4 * 4]) = h;
    }
  }
  __syncthreads();   // (1) tile0 staged

  for (int tile = tile0; tile < tile1; ++tile) {
    const int block0 = tile * 64;
    const int nvalid = min(64, nnodes - block0);
    const bool havenext = (tile + 1 < tile1);
    const int nblock0 = block0 + 64;

    // prefetch HALF of next tile (rows 0..31) into regs; stays in flight
    // across GEMM + scan (no waitcnt until the write phase after barrier 4)
    f32x4 pf[8];
    #pragma unroll
    for (int it = 0; it < 8; ++it) {
      int idx = it * 256 + t;
      int row = idx >> 6;
      int c4  = idx & 63;
      pf[it] = (f32x4){0.f, 0.f, 0.f, 0.f};
      if (havenext && nblock0 + row < nnodes)
        pf[it] = *(reinterpret_cast<const f32x4*>(x) + (size_t)(nblock0 + row) * 64 + c4);
    }

    // GEMM: wave cg computes h[:, cg*64 .. cg*64+64) for all 64 nodes (4 mt)
    #pragma unroll
    for (int mt = 0; mt < 4; ++mt) {
      f32x4 acc[4] = {{0,0,0,0},{0,0,0,0},{0,0,0,0},{0,0,0,0}};
      #pragma unroll
      for (int kk = 0; kk < 8; ++kk) {
        short8 af = *reinterpret_cast<const short8*>(&sX[mt * 16 + m][kk * 32 + quad * 8]);
        #pragma unroll
        for (int nb = 0; nb < 4; ++nb)
          acc[nb] = __builtin_amdgcn_mfma_f32_16x16x32_bf16(af, Bfrag[kk][nb], acc[nb], 0, 0, 0);
      }
      score_store(acc, b1r, w2r, &sScoreP[cg][mt * 16], m, quad);
    }
    __syncthreads();   // (2) score partials ready

    if (t < 64) {   // wave 0 exactly
      float s = sScoreP[0][t] + sScoreP[1][t] + sScoreP[2][t] + sScoreP[3][t] + b2;
      sAw[t] = 1.f / (1.f + __expf(-s));

      // run structure via ballot over sorted batch ids
      int b = sBatch[t];
      bool valid = t < nvalid;
      bool isStart = valid && (t == 0 || sBatch[t - 1] != b);
      unsigned long long mask = __ballot(isStart);
      if (isStart) {
        int rid = __popcll(mask & ((1ull << t) - 1ull));
        sRunStart[rid] = t;
        sSeg[rid] = b;
        unsigned long long rest = (t < 63) ? (mask >> (t + 1)) : 0ull;
        int nxt = rest ? (t + __ffsll((long long)rest)) : nvalid;   // next start or end
        atomicAdd(&cntbuf[b], (float)(nxt - t));                    // exact run length
      }
      if (t == 0) { int nr = __popcll(mask); sNruns = nr; sRunStart[nr] = nvalid; }
    }
    __syncthreads();   // (3) aw + run table ready

    // pooling scan: wave cg covers its 64 chans x all nvalid nodes; every run
    // flushed directly via atomics (associative ops)
    {
      const int nr = sNruns;
      for (int r = 0; r < nr; ++r) {
        int rs = sRunStart[r];
        int re = sRunStart[r + 1];                 // <= nvalid by construction
        float aS = 0.f, aA = 0.f, aM = -INFINITY;
        for (int i = rs; i < re; ++i) {
          float xv = bf2f(sX[i][chan]);
          float awv = sAw[i];                      // broadcast read
          aS += xv;
          aA = fmaf(xv, awv, aA);
          aM = fmaxf(aM, xv);
        }
        int seg = sSeg[r];
        atomicAdd(&sumbuf[(size_t)seg * 256 + chan], aS);
        atomicAdd(&attbuf[(size_t)seg * 256 + chan], aA);
        atomicMax(&maxkey[(size_t)seg * 256 + chan], fkey(aM));
      }
    }
    __syncthreads();   // (4) all reads of sX/sBatch done

    if (havenext) {    // block-uniform condition
      const int nv2 = min(64, nnodes - nblock0);
      if (t < 64) sBatch[t] = (t < nv2) ? batch[nblock0 + t] : -1;
      // write prefetched half (rows 0..31)
      #pragma unroll
      for (int it = 0; it < 8; ++it) {
        int idx = it * 256 + t;
        int row = idx >> 6;
        int c4  = idx & 63;
        ushort4 h;
        h.x = f2bf(pf[it].x); h.y = f2bf(pf[it].y);
        h.z = f2bf(pf[it].z); h.w = f2bf(pf[it].w);
        *reinterpret_cast<ushort4*>(&sX[row][c4 * 4]) = h;
      }
      // load + write second half (rows 32..63)
      #pragma unroll
      for (int it = 8; it < 16; ++it) {
        int idx = it * 256 + t;
        int row = idx >> 6;
        int c4  = idx & 63;
        f32x4 v = {0.f, 0.f, 0.f, 0.f};
        if (nblock0 + row < nnodes)
          v = *(reinterpret_cast<const f32x4*>(x) + (size_t)(nblock0 + row) * 64 + c4);
        ushort4 h;
        h.x = f2bf(v.x); h.y = f2bf(v.y); h.z = f2bf(v.z); h.w = f2bf(v.w);
        *reinterpret_cast<ushort4*>(&sX[row][c4 * 4]) = h;
      }
      __syncthreads();   // (1) next tile staged
    }
  }
}

// ---------------------------------------------------------------------------
// Final MLP: out[g] = relu(comb[g] @ W1f + b1f) @ W2f + b2f, 4 graphs/block
// (1024 blocks -> good latency hiding), rank-1-update formulation.
// ---------------------------------------------------------------------------
__global__ __launch_bounds__(256, 4)
void final_mlp_kernel(const float* __restrict__ attbuf, const float* __restrict__ sumbuf,
                      const unsigned* __restrict__ maxkey, const float* __restrict__ cntbuf,
                      const float* __restrict__ W1f, const float* __restrict__ b1f,
                      const float* __restrict__ W2f, const float* __restrict__ b2f,
                      float* __restrict__ out) {
  __shared__ float sComb[4 * 768];
  __shared__ float sHid[4 * 256];
  const int t = threadIdx.x;
  const int g0 = blockIdx.x * 4;

  for (int idx = t; idx < 4 * 768; idx += 256) {
    int g = idx / 768;
    int k = idx - g * 768;
    int gg = g0 + g;
    float cnt = cntbuf[gg];
    float v;
    if (k < 256) {
      v = attbuf[(size_t)gg * 256 + k];
    } else if (k < 512) {
      v = sumbuf[(size_t)gg * 256 + (k - 256)] / fmaxf(cnt, 1.f);
    } else {
      unsigned u = maxkey[(size_t)gg * 256 + (k - 512)];
      unsigned b = (u & 0x80000000u) ? (u & 0x7fffffffu) : ~u;
      v = (cnt > 0.f) ? __uint_as_float(b) : 0.f;   // empty segment -> 0
    }
    sComb[idx] = v;
  }
  __syncthreads();

  float acc[4] = {0, 0, 0, 0};
  #pragma unroll 4
  for (int k = 0; k < 768; ++k) {
    float wv = W1f[k * 256 + t];
    #pragma unroll
    for (int g = 0; g < 4; ++g) acc[g] = fmaf(sComb[g * 768 + k], wv, acc[g]);
  }
  float bb = b1f[t];
  #pragma unroll
  for (int g = 0; g < 4; ++g) sHid[g * 256 + t] = fmaxf(acc[g] + bb, 0.f);
  __syncthreads();

  float acc2[4] = {0, 0, 0, 0};
  #pragma unroll 4
  for (int k = 0; k < 256; ++k) {
    float wv = W2f[k * 256 + t];
    #pragma unroll
    for (int g = 0; g < 4; ++g) acc2[g] = fmaf(sHid[g * 256 + k], wv, acc2[g]);
  }
  float bo = b2f[t];
  #pragma unroll
  for (int g = 0; g < 4; ++g) out[(size_t)(g0 + g) * 256 + t] = acc2[g] + bo;
}

// ---------------------------------------------------------------------------
extern "C" void kernel_launch(void* const* d_in, const int* in_sizes, int n_in,
                              void* d_out, int out_size, void* d_ws, size_t ws_size,
                              hipStream_t stream) {
  const float* x   = (const float*)d_in[0];
  const int* batch = (const int*)d_in[1];
  const float* W1a = (const float*)d_in[2];
  const float* b1a = (const float*)d_in[3];
  const float* W2a = (const float*)d_in[4];
  const float* b2a = (const float*)d_in[5];
  const float* W1f = (const float*)d_in[6];
  const float* b1f = (const float*)d_in[7];
  const float* W2f = (const float*)d_in[8];
  const float* b2f = (const float*)d_in[9];
  float* out = (float*)d_out;

  const int N = in_sizes[0] / 256;
  const int G = out_size / 256;

  char* ws = (char*)d_ws;
  float* attbuf = (float*)ws;
  float* sumbuf = attbuf + (size_t)G * 256;
  unsigned* maxkey = (unsigned*)(sumbuf + (size_t)G * 256);
  float* cntbuf = (float*)(maxkey + (size_t)G * 256);
  unsigned short* packedB = (unsigned short*)(cntbuf + G);

  size_t zero_bytes = ((size_t)G * 256 * 3 + G) * sizeof(float);
  (void)hipMemsetAsync(d_ws, 0, zero_bytes, stream);

  prep_b_kernel<<<256, 256, 0, stream>>>(W1a, packedB);

  int ntiles = (N + 63) / 64;        // 64-node tiles
  const int nblocks = 1024;
  int tpb = (ntiles + nblocks - 1) / nblocks;
  phase_a_kernel<<<nblocks, 256, 0, stream>>>(x, batch, packedB, b1a, W2a, b2a,
                                              attbuf, sumbuf, maxkey, cntbuf,
                                              N, ntiles, tpb);

  final_mlp_kernel<<<G / 4, 256, 0, stream>>>(attbuf, sumbuf, maxkey, cntbuf,
                                              W1f, b1f, W2f, b2f, out);
}